// Round 6
// baseline (351.979 us; speedup 1.0000x reference)
//
#include <hip/hip_runtime.h>
#include <math.h>

#define N_PTS 65536
#define M_IND 1024
#define KNN 16
#define JITTER 1e-4f

// Packed lower-triangular Su: P[i*(i+1)/2 + j], j <= i.
#define PACKED_FLOATS (M_IND * (M_IND + 1) / 2)               // 524800
#define PACKED_BYTES  ((size_t)PACKED_FLOATS * sizeof(float)) // 2,099,200 B

// ---------------------------------------------------------------------------
// Kernel A: packed Su = tril(Lu Lu^T), Lu = tril(Lu_raw,-1)+diag(exp(diag)).
// 32x32 tiles (528 blocks) x 512 threads = 2 k-groups of 256. Each group
// accumulates chunks c = g mod 2; deterministic LDS reduction at the end
// (no atomics -> bitwise-stable across graph replays). 16 waves/CU.
// ---------------------------------------------------------------------------
#define TSU 32
#define SU_BLOCKS 528   // 32*33/2 triangular tiles

__global__ __launch_bounds__(512) void su_kernel(const float* __restrict__ Lu_raw,
                                                 float* __restrict__ P) {
    __shared__ float As[2][TSU][36];   // stride 36 keeps float4 rows aligned
    __shared__ float Bs[2][TSU][36];
    __shared__ float Red[TSU][TSU];

    int bid = blockIdx.x;
    int rt = (int)((sqrtf(8.0f * (float)bid + 1.0f) - 1.0f) * 0.5f);
    while ((rt + 1) * (rt + 2) / 2 <= bid) ++rt;
    while (rt * (rt + 1) / 2 > bid) --rt;
    int ct = bid - rt * (rt + 1) / 2;   // ct <= rt
    int i0 = rt * TSU, j0 = ct * TSU;

    int tid = threadIdx.x;
    int g = tid >> 8, lt = tid & 255;   // k-group, lane-in-group
    int tx = lt & 15, ty = lt >> 4;     // 16x16 threads, 2x2 outputs
    int sr = lt >> 3, sc = (lt & 7) << 2;  // staging: row 0..31, col4 0..28
    float a00 = 0.f, a01 = 0.f, a10 = 0.f, a11 = 0.f;

    int nch = ct + 1;                   // k-chunks of 32 (k <= j0+31)
    int npairs = (nch + 1) >> 1;
    for (int cp = 0; cp < npairs; ++cp) {
        int c = cp * 2 + g;
        bool act = c < nch;
        if (act) {
            int k0 = c << 5;
            int gi = i0 + sr, gj = j0 + sr, gk = k0 + sc;
            float4 av = *(const float4*)(Lu_raw + (unsigned)gi * M_IND + gk);
            float4 bv = *(const float4*)(Lu_raw + (unsigned)gj * M_IND + gk);
            float aa[4] = {av.x, av.y, av.z, av.w};
            float bb[4] = {bv.x, bv.y, bv.z, bv.w};
            #pragma unroll
            for (int q = 0; q < 4; ++q) {
                int k = gk + q;
                aa[q] = (k < gi) ? aa[q] : ((k == gi) ? __expf(aa[q]) : 0.0f);
                bb[q] = (k < gj) ? bb[q] : ((k == gj) ? __expf(bb[q]) : 0.0f);
            }
            *(float4*)&As[g][sr][sc] = make_float4(aa[0], aa[1], aa[2], aa[3]);
            *(float4*)&Bs[g][sr][sc] = make_float4(bb[0], bb[1], bb[2], bb[3]);
        }
        __syncthreads();
        if (act) {
            #pragma unroll
            for (int kk = 0; kk < 32; ++kk) {
                float x0 = As[g][ty][kk], x1 = As[g][ty + 16][kk];
                float y0 = Bs[g][tx][kk], y1 = Bs[g][tx + 16][kk];
                a00 = fmaf(x0, y0, a00); a01 = fmaf(x0, y1, a01);
                a10 = fmaf(x1, y0, a10); a11 = fmaf(x1, y1, a11);
            }
        }
        __syncthreads();
    }

    if (g == 1) {
        Red[ty][tx] = a00;      Red[ty][tx + 16] = a01;
        Red[ty + 16][tx] = a10; Red[ty + 16][tx + 16] = a11;
    }
    __syncthreads();
    if (g == 0) {
        a00 += Red[ty][tx];      a01 += Red[ty][tx + 16];
        a10 += Red[ty + 16][tx]; a11 += Red[ty + 16][tx + 16];
        int ia = i0 + ty, ib = i0 + ty + 16;
        int ja = j0 + tx, jb = j0 + tx + 16;
        if (ja <= ia) P[((unsigned)ia * (ia + 1) >> 1) + ja] = a00;
        if (jb <= ia) P[((unsigned)ia * (ia + 1) >> 1) + jb] = a01;
        if (ja <= ib) P[((unsigned)ib * (ib + 1) >> 1) + ja] = a10;
        if (jb <= ib) P[((unsigned)ib * (ib + 1) >> 1) + jb] = a11;
    }
}

// ---------------------------------------------------------------------------
// Sorting-network helpers.
// ---------------------------------------------------------------------------
__device__ __forceinline__ void ce(unsigned long long& x, unsigned long long& y) {
    unsigned long long a = x, b = y;
    bool c = a < b;
    x = c ? a : b;
    y = c ? b : a;
}
__device__ __forceinline__ void ce(float& x, float& y) {
    float a = fminf(x, y), b = fmaxf(x, y);
    x = a; y = b;
}

// Batcher odd-even mergesort, n=16, ascending.
template <typename KT>
__device__ __forceinline__ void sort16(KT* a) {
    #pragma unroll
    for (int p = 1; p < 16; p <<= 1)
        #pragma unroll
        for (int k = p; k >= 1; k >>= 1)
            #pragma unroll
            for (int j = k & (p - 1); j + k < 16; j += 2 * k)
                #pragma unroll
                for (int i = 0; i < k; ++i)
                    if (i + j + k < 16)
                        if (((i + j) / (2 * p)) == ((i + j + k) / (2 * p)))
                            ce(a[i + j], a[i + j + k]);
}

// Bitonic cleanup for 16 (input: min of two ascending seqs, reverse-paired).
template <typename KT>
__device__ __forceinline__ void cleanup16(KT* a) {
    #pragma unroll
    for (int d = 8; d >= 1; d >>= 1)
        #pragma unroll
        for (int i = 0; i < 16; ++i)
            if ((i & d) == 0) ce(a[i], a[i | d]);
}

// Identical-bits distance (used by pass 1, pass 2, and the fallback).
__device__ __forceinline__ float distf(float4 z, float x0, float x1, float x2, float xq) {
    float dot = fmaf(x0, z.x, fmaf(x1, z.y, x2 * z.z));
    return fmaxf(fmaf(-2.0f, dot, xq + z.w), 0.0f);
}

// ---------------------------------------------------------------------------
// Kernel B: two-pass threshold selection + local GP solve.
// 4 subs/point; pass 1 builds 16 f32 class-minima per sub, quad-merges to
// T* = 16th-smallest of 64 minima (provable upper bound on the true 16th-
// smallest distance); pass 2 collects {d <= T*} (~19/point) into per-sub LDS
// buffers; one u64 sort16 + quad merge gives the exact (dist,idx)-ordered
// top-16. Overflow (cnt>12 in a sub, rare) falls back to an exact serial scan.
// ---------------------------------------------------------------------------
#define PTS_PER_BLK 128
#define SUBCAP 12

template <bool USE_WS>
__global__ __launch_bounds__(512, 2) void vnngp_kernel(const float* __restrict__ X,
                                                       const float* __restrict__ Z,
                                                       const float* __restrict__ mu,
                                                       const float* __restrict__ P,
                                                       const float* __restrict__ Lu_raw,
                                                       float* __restrict__ out) {
    __shared__ float4 Zs[M_IND];                       // 16 KB
    __shared__ float mus[M_IND];                       // 4 KB
    __shared__ unsigned long long qb[PTS_PER_BLK][49]; // 49 KB: 4x12 collect + hand[0..15]
    int tid = threadIdx.x;
    for (int r = tid; r < M_IND; r += 512) {
        float zx = Z[r * 3 + 0], zy = Z[r * 3 + 1], zz = Z[r * 3 + 2];
        Zs[r] = make_float4(zx, zy, zz, zx * zx + zy * zy + zz * zz);
        mus[r] = mu[r];
    }
    __syncthreads();

    {
        int pt = tid >> 2, sub = tid & 3;
        int n = blockIdx.x * PTS_PER_BLK + pt;
        float x0 = X[n * 3 + 0], x1 = X[n * 3 + 1], x2 = X[n * 3 + 2];
        float xq = fmaf(x0, x0, fmaf(x1, x1, x2 * x2));
        int mbase = sub << 8;
        int rot = sub << 1;   // bank phase: subs land on disjoint bank quads

        // ---- Pass 1: 16 interleaved class minima (f32) ----
        float T[16];
        #pragma unroll
        for (int j = 0; j < 16; ++j) T[j] = 3.4e38f;
        #pragma unroll 1
        for (int c = 0; c < 16; ++c) {
            int base = mbase + (c << 4);
            #pragma unroll
            for (int j = 0; j < 16; ++j) {
                int m = base + ((j + rot) & 15);
                float d = distf(Zs[m], x0, x1, x2, xq);
                T[j] = fminf(T[j], d);
            }
        }
        sort16(T);
        #pragma unroll
        for (int round = 1; round <= 2; round <<= 1) {
            float o[16];
            #pragma unroll
            for (int i = 0; i < 16; ++i) o[i] = __shfl_xor(T[i], round, 64);
            #pragma unroll
            for (int i = 0; i < 16; ++i) T[i] = fminf(T[i], o[15 - i]);
            cleanup16(T);
        }
        float Tstar = T[15];   // >= exact 16th-smallest distance of this point

        // ---- Pass 2: collect d <= Tstar (identical distance bits) ----
        int cnt = 0;
        #pragma unroll 1
        for (int c = 0; c < 16; ++c) {
            int base = mbase + (c << 4);
            #pragma unroll
            for (int j = 0; j < 16; ++j) {
                int m = base + ((j + rot) & 15);
                float d = distf(Zs[m], x0, x1, x2, xq);
                if (d <= Tstar) {
                    if (cnt < SUBCAP)
                        qb[pt][sub * SUBCAP + cnt] =
                            ((unsigned long long)__float_as_uint(d) << 32) | (unsigned)m;
                    ++cnt;
                }
            }
        }

        int ovf = cnt > SUBCAP ? 1 : 0;
        ovf |= __shfl_xor(ovf, 1, 64);
        ovf |= __shfl_xor(ovf, 2, 64);

        if (!ovf) {
            unsigned long long C[16];
            #pragma unroll
            for (int i = 0; i < 16; ++i) {
                unsigned long long v = (i < SUBCAP) ? qb[pt][sub * SUBCAP + i] : ~0ULL;
                C[i] = (i < cnt) ? v : ~0ULL;
            }
            sort16(C);
            #pragma unroll
            for (int round = 1; round <= 2; round <<= 1) {
                unsigned long long o[16];
                #pragma unroll
                for (int i = 0; i < 16; ++i) o[i] = __shfl_xor(C[i], round, 64);
                #pragma unroll
                for (int i = 0; i < 16; ++i) {
                    unsigned long long b = o[15 - i];
                    C[i] = C[i] < b ? C[i] : b;
                }
                cleanup16(C);
            }
            if (sub == 0) {
                #pragma unroll
                for (int i = 0; i < 16; ++i) qb[pt][i] = C[i];
            }
        } else if (sub == 0) {
            // Rare exact fallback: full serial scan with branchless insert.
            unsigned long long R[16];
            #pragma unroll
            for (int i = 0; i < 16; ++i) R[i] = ~0ULL;
            for (int m = 0; m < M_IND; ++m) {
                float d = distf(Zs[m], x0, x1, x2, xq);
                unsigned long long kk =
                    ((unsigned long long)__float_as_uint(d) << 32) | (unsigned)m;
                if (kk < R[15]) {
                    #pragma unroll
                    for (int j = 0; j < 16; ++j) {
                        unsigned long long t = R[j];
                        bool cc = kk < t;
                        R[j] = cc ? kk : t;
                        kk = cc ? t : kk;
                    }
                }
            }
            #pragma unroll
            for (int i = 0; i < 16; ++i) qb[pt][i] = R[i];
        }
    }
    __syncthreads();
    if (tid >= PTS_PER_BLK) return;

    // ---- Phase 2: local GP, one thread per point ----
    int n = blockIdx.x * PTS_PER_BLK + tid;
    int idx[KNN];
    float kv[KNN];
    float nx[KNN], ny[KNN], nz[KNN], nq[KNN];
    #pragma unroll
    for (int a = 0; a < KNN; ++a) {
        unsigned long long k = qb[tid][a];
        idx[a] = (int)(k & 0xFFFFFFFFULL);
        float d = __uint_as_float((unsigned)(k >> 32));
        kv[a] = __expf(-0.5f * d);            // lKxz entries
        float4 z = Zs[idx[a]];
        nx[a] = z.x; ny[a] = z.y; nz[a] = z.z; nq[a] = z.w;
    }

    // A = lKzz + JITTER*I (lower tri); lKzz diag carries global jitter from
    // Kzz_j = L L^T -> diag = 1 + 2*JITTER.
    float A[KNN * (KNN + 1) / 2];
    #pragma unroll
    for (int r = 0; r < KNN; ++r) {
        A[r * (r + 1) / 2 + r] = 1.0f + 2.0f * JITTER;
        #pragma unroll
        for (int c = 0; c < r; ++c) {
            float dd = nq[r] + nq[c]
                     - 2.0f * (nx[r] * nx[c] + ny[r] * ny[c] + nz[r] * nz[c]);
            dd = fmaxf(dd, 0.0f);
            A[r * (r + 1) / 2 + c] = __expf(-0.5f * dd);
        }
    }

    // In-place Cholesky; store 1/L[c][c] in the diagonal slot.
    #pragma unroll
    for (int c = 0; c < KNN; ++c) {
        float diag = A[c * (c + 1) / 2 + c];
        #pragma unroll
        for (int k = 0; k < c; ++k) {
            float l = A[c * (c + 1) / 2 + k];
            diag = fmaf(-l, l, diag);
        }
        float s = sqrtf(fmaxf(diag, 1e-12f));
        float rinv = 1.0f / s;
        A[c * (c + 1) / 2 + c] = rinv;
        #pragma unroll
        for (int r = c + 1; r < KNN; ++r) {
            float v = A[r * (r + 1) / 2 + c];
            #pragma unroll
            for (int k = 0; k < c; ++k)
                v = fmaf(-A[r * (r + 1) / 2 + k], A[c * (c + 1) / 2 + k], v);
            A[r * (r + 1) / 2 + c] = v * rinv;
        }
    }

    // Solve A w = kv (forward then backward).
    float w[KNN];
    #pragma unroll
    for (int r = 0; r < KNN; ++r) {
        float v = kv[r];
        #pragma unroll
        for (int c = 0; c < r; ++c) v = fmaf(-A[r * (r + 1) / 2 + c], w[c], v);
        w[r] = v * A[r * (r + 1) / 2 + r];
    }
    #pragma unroll
    for (int r = KNN - 1; r >= 0; --r) {
        float v = w[r];
        #pragma unroll
        for (int c = r + 1; c < KNN; ++c) v = fmaf(-A[c * (c + 1) / 2 + r], w[c], v);
        w[r] = v * A[r * (r + 1) / 2 + r];
    }

    // W lKzz W^T = w.k - JITTER*||w||^2   (A w = k, lKzz = A - JITTER*I)
    float wk = 0.f, ww = 0.f, mean = 0.f;
    #pragma unroll
    for (int a = 0; a < KNN; ++a) {
        wk = fmaf(w[a], kv[a], wk);
        ww = fmaf(w[a], w[a], ww);
        mean = fmaf(w[a], mus[idx[a]], mean);
    }

    // qs = w^T Su[idx,idx] w
    float qs = 0.f;
    if (USE_WS) {
        #pragma unroll
        for (int r = 0; r < KNN; ++r) {
            int a = idx[r];
            float wr = w[r];
            float rowacc = 0.f;
            #pragma unroll
            for (int c = 0; c < r; ++c) {
                int b = idx[c];
                int hi = a > b ? a : b;
                int lo = a > b ? b : a;
                rowacc = fmaf(w[c], P[((unsigned)hi * (hi + 1) >> 1) + lo], rowacc);
            }
            qs = fmaf(wr, fmaf(wr, P[((unsigned)a * (a + 1) >> 1) + a], 2.0f * rowacc), qs);
        }
    } else {
        // On-demand fallback: qs = sum_k (sum_a w_a * Lu[idx_a, k])^2
        int si[KNN]; float sw[KNN];
        #pragma unroll
        for (int a = 0; a < KNN; ++a) { si[a] = idx[a]; sw[a] = w[a]; }
        #pragma unroll
        for (int a = 1; a < KNN; ++a) {
            int iv = si[a]; float wv = sw[a];
            int b = a - 1;
            while (b >= 0 && si[b] > iv) { si[b + 1] = si[b]; sw[b + 1] = sw[b]; --b; }
            si[b + 1] = iv; sw[b + 1] = wv;
        }
        int s = 0;
        int kend = si[KNN - 1];
        for (int k = 0; k <= kend; ++k) {
            float v = 0.f;
            if (s < KNN && si[s] == k) {
                v = sw[s] * __expf(Lu_raw[(unsigned)k * M_IND + k]);
                ++s;
            }
            for (int a = s; a < KNN; ++a)
                v = fmaf(sw[a], Lu_raw[(unsigned)si[a] * M_IND + k], v);
            qs = fmaf(v, v, qs);
        }
    }

    float cov = 1.0f - (wk - JITTER * ww) + qs;
    float sd = sqrtf(fmaxf(cov, 0.05f));
    out[n] = mean;
    out[N_PTS + n] = sd;
}

// ---------------------------------------------------------------------------
extern "C" void kernel_launch(void* const* d_in, const int* in_sizes, int n_in,
                              void* d_out, int out_size, void* d_ws, size_t ws_size,
                              hipStream_t stream) {
    const float* X      = (const float*)d_in[0];
    const float* Z      = (const float*)d_in[1];
    const float* Lu_raw = (const float*)d_in[2];
    const float* mu     = (const float*)d_in[3];
    float* out = (float*)d_out;

    if (ws_size >= PACKED_BYTES) {
        float* P = (float*)d_ws;   // packed lower-tri Su
        su_kernel<<<SU_BLOCKS, 512, 0, stream>>>(Lu_raw, P);
        vnngp_kernel<true><<<N_PTS / PTS_PER_BLK, 512, 0, stream>>>(X, Z, mu, P, Lu_raw, out);
    } else {
        vnngp_kernel<false><<<N_PTS / PTS_PER_BLK, 512, 0, stream>>>(X, Z, mu, nullptr, Lu_raw, out);
    }
}

// Round 7
// 204.241 us; speedup vs baseline: 1.7233x; 1.7233x over previous
//
#include <hip/hip_runtime.h>
#include <math.h>

#define N_PTS 65536
#define M_IND 1024
#define KNN 16
#define JITTER 1e-4f

// Packed lower-triangular Su: P[i*(i+1)/2 + j], j <= i.
#define PACKED_FLOATS (M_IND * (M_IND + 1) / 2)               // 524800
#define PACKED_BYTES  ((size_t)PACKED_FLOATS * sizeof(float)) // 2,099,200 B

// ---------------------------------------------------------------------------
// Kernel A: packed Su = tril(Lu Lu^T), Lu = tril(Lu_raw,-1)+diag(exp(diag)).
// 32x32 tiles (528 blocks) x 256 threads, 2x2 outputs/thread, BK=32.
// Inner loop uses ds_read_b128 (4 kk per read): 4 b128 per 16 fma instead of
// 16 scalar ds_read_b32 -> ~4x fewer DS issue cycles (R6 was LDS-issue-bound).
// Register prefetch of the next chunk overlaps global latency with compute.
// ---------------------------------------------------------------------------
#define TSU 32
#define SU_BLOCKS 528   // 32*33/2 triangular tiles

__global__ __launch_bounds__(256) void su_kernel(const float* __restrict__ Lu_raw,
                                                 float* __restrict__ P) {
    __shared__ float As[TSU][36];   // stride 36: float4-aligned rows, banks spread
    __shared__ float Bs[TSU][36];

    int bid = blockIdx.x;
    int rt = (int)((sqrtf(8.0f * (float)bid + 1.0f) - 1.0f) * 0.5f);
    while ((rt + 1) * (rt + 2) / 2 <= bid) ++rt;
    while (rt * (rt + 1) / 2 > bid) --rt;
    int ct = bid - rt * (rt + 1) / 2;   // ct <= rt
    int i0 = rt * TSU, j0 = ct * TSU;

    int tid = threadIdx.x;
    int tx = tid & 15, ty = tid >> 4;      // 16x16 threads, 2x2 outputs
    int sr = tid >> 3, sc = (tid & 7) << 2;  // staging: row 0..31, col 0,4,..28
    float a00 = 0.f, a01 = 0.f, a10 = 0.f, a11 = 0.f;

    int nch = ct + 1;                      // k-chunks of 32 (k <= j0+31)
    int gi = i0 + sr, gj = j0 + sr;
    float4 pa = *(const float4*)(Lu_raw + (unsigned)gi * M_IND + sc);
    float4 pb = *(const float4*)(Lu_raw + (unsigned)gj * M_IND + sc);

    for (int c = 0; c < nch; ++c) {
        int gk = (c << 5) + sc;
        float aa[4] = {pa.x, pa.y, pa.z, pa.w};
        float bb[4] = {pb.x, pb.y, pb.z, pb.w};
        #pragma unroll
        for (int q = 0; q < 4; ++q) {
            int k = gk + q;
            aa[q] = (k < gi) ? aa[q] : ((k == gi) ? __expf(aa[q]) : 0.0f);
            bb[q] = (k < gj) ? bb[q] : ((k == gj) ? __expf(bb[q]) : 0.0f);
        }
        *(float4*)&As[sr][sc] = make_float4(aa[0], aa[1], aa[2], aa[3]);
        *(float4*)&Bs[sr][sc] = make_float4(bb[0], bb[1], bb[2], bb[3]);
        __syncthreads();
        if (c + 1 < nch) {                 // prefetch next chunk
            int kn = ((c + 1) << 5) + sc;
            pa = *(const float4*)(Lu_raw + (unsigned)gi * M_IND + kn);
            pb = *(const float4*)(Lu_raw + (unsigned)gj * M_IND + kn);
        }
        #pragma unroll
        for (int kk = 0; kk < 32; kk += 4) {
            float4 av0 = *(const float4*)&As[ty][kk];
            float4 av1 = *(const float4*)&As[ty + 16][kk];
            float4 bv0 = *(const float4*)&Bs[tx][kk];
            float4 bv1 = *(const float4*)&Bs[tx + 16][kk];
            a00 = fmaf(av0.x, bv0.x, fmaf(av0.y, bv0.y, fmaf(av0.z, bv0.z, fmaf(av0.w, bv0.w, a00))));
            a01 = fmaf(av0.x, bv1.x, fmaf(av0.y, bv1.y, fmaf(av0.z, bv1.z, fmaf(av0.w, bv1.w, a01))));
            a10 = fmaf(av1.x, bv0.x, fmaf(av1.y, bv0.y, fmaf(av1.z, bv0.z, fmaf(av1.w, bv0.w, a10))));
            a11 = fmaf(av1.x, bv1.x, fmaf(av1.y, bv1.y, fmaf(av1.z, bv1.z, fmaf(av1.w, bv1.w, a11))));
        }
        __syncthreads();
    }

    int ia = i0 + ty, ib = i0 + ty + 16;
    int ja = j0 + tx, jb = j0 + tx + 16;
    if (ja <= ia) P[((unsigned)ia * (ia + 1) >> 1) + ja] = a00;
    if (jb <= ia) P[((unsigned)ia * (ia + 1) >> 1) + jb] = a01;
    if (ja <= ib) P[((unsigned)ib * (ib + 1) >> 1) + ja] = a10;
    if (jb <= ib) P[((unsigned)ib * (ib + 1) >> 1) + jb] = a11;
}

// ---------------------------------------------------------------------------
// Sorting-network helpers.
// ---------------------------------------------------------------------------
__device__ __forceinline__ void ce(unsigned long long& x, unsigned long long& y) {
    unsigned long long a = x, b = y;
    bool c = a < b;
    x = c ? a : b;
    y = c ? b : a;
}
__device__ __forceinline__ void ce(float& x, float& y) {
    float a = fminf(x, y), b = fmaxf(x, y);
    x = a; y = b;
}

// Batcher odd-even mergesort, n=16, ascending.
template <typename KT>
__device__ __forceinline__ void sort16(KT* a) {
    #pragma unroll
    for (int p = 1; p < 16; p <<= 1)
        #pragma unroll
        for (int k = p; k >= 1; k >>= 1)
            #pragma unroll
            for (int j = k & (p - 1); j + k < 16; j += 2 * k)
                #pragma unroll
                for (int i = 0; i < k; ++i)
                    if (i + j + k < 16)
                        if (((i + j) / (2 * p)) == ((i + j + k) / (2 * p)))
                            ce(a[i + j], a[i + j + k]);
}

// Bitonic cleanup for 16 (input: min of two ascending seqs, reverse-paired).
template <typename KT>
__device__ __forceinline__ void cleanup16(KT* a) {
    #pragma unroll
    for (int d = 8; d >= 1; d >>= 1)
        #pragma unroll
        for (int i = 0; i < 16; ++i)
            if ((i & d) == 0) ce(a[i], a[i | d]);
}

// Identical-bits distance (used by pass 1, pass 2, read-back, and fallback).
__device__ __forceinline__ float distf(float4 z, float x0, float x1, float x2, float xq) {
    float dot = fmaf(x0, z.x, fmaf(x1, z.y, x2 * z.z));
    return fmaxf(fmaf(-2.0f, dot, xq + z.w), 0.0f);
}

// ---------------------------------------------------------------------------
// Kernel B: two-pass threshold selection + local GP solve.
// 4 subs/point. Pass 1: 16 f32 class minima/sub, quad-merged -> Tstar =
// 16th-smallest of 64 minima (provable upper bound on the true 16th-smallest).
// Pass 2: collect indices of {d <= Tstar} as u16 (cap 16/sub) into a 136 B/pt
// LDS region; read back, recompute d (identical bits), u64 sort16 + quad
// merge -> exact (dist,idx)-ordered top-16, written over the same region.
// LDS = 16K Zs + 4K mus + 17K qb = 37.9 KB -> 4 blocks/CU (R6's 69 KB halved
// occupancy and made the kernel latency-bound; this restores it).
// ---------------------------------------------------------------------------
#define PTS_PER_BLK 128
#define QSTRIDE 17   // u64 words per point row (136 B): pad kills phase-2 64-way conflicts

template <bool USE_WS>
__global__ __launch_bounds__(512, 2) void vnngp_kernel(const float* __restrict__ X,
                                                       const float* __restrict__ Z,
                                                       const float* __restrict__ mu,
                                                       const float* __restrict__ P,
                                                       const float* __restrict__ Lu_raw,
                                                       float* __restrict__ out) {
    __shared__ float4 Zs[M_IND];                            // 16 KB
    __shared__ float mus[M_IND];                            // 4 KB
    __shared__ unsigned long long qb[PTS_PER_BLK * QSTRIDE]; // 17 KB
    int tid = threadIdx.x;
    for (int r = tid; r < M_IND; r += 512) {
        float zx = Z[r * 3 + 0], zy = Z[r * 3 + 1], zz = Z[r * 3 + 2];
        Zs[r] = make_float4(zx, zy, zz, zx * zx + zy * zy + zz * zz);
        mus[r] = mu[r];
    }
    __syncthreads();

    {
        int pt = tid >> 2, sub = tid & 3;
        int n = blockIdx.x * PTS_PER_BLK + pt;
        float x0 = X[n * 3 + 0], x1 = X[n * 3 + 1], x2 = X[n * 3 + 2];
        float xq = fmaf(x0, x0, fmaf(x1, x1, x2 * x2));
        int mbase = sub << 8;
        int rot = sub << 1;   // bank phase: subs land on disjoint bank quads

        // ---- Pass 1: 16 interleaved class minima (f32) ----
        float T[16];
        #pragma unroll
        for (int j = 0; j < 16; ++j) T[j] = 3.4e38f;
        #pragma unroll 1
        for (int c = 0; c < 16; ++c) {
            int base = mbase + (c << 4);
            #pragma unroll
            for (int j = 0; j < 16; ++j) {
                int m = base + ((j + rot) & 15);
                float d = distf(Zs[m], x0, x1, x2, xq);
                T[j] = fminf(T[j], d);
            }
        }
        sort16(T);
        #pragma unroll
        for (int round = 1; round <= 2; round <<= 1) {
            float o[16];
            #pragma unroll
            for (int i = 0; i < 16; ++i) o[i] = __shfl_xor(T[i], round, 64);
            #pragma unroll
            for (int i = 0; i < 16; ++i) T[i] = fminf(T[i], o[15 - i]);
            cleanup16(T);
        }
        float Tstar = T[15];   // >= exact 16th-smallest distance of this point

        // ---- Pass 2: collect indices with d <= Tstar (u16, cap 16/sub) ----
        unsigned short* myc = ((unsigned short*)qb) + pt * (QSTRIDE * 4) + sub * 16;
        int cnt = 0;
        #pragma unroll 1
        for (int c = 0; c < 16; ++c) {
            int base = mbase + (c << 4);
            #pragma unroll
            for (int j = 0; j < 16; ++j) {
                int m = base + ((j + rot) & 15);
                float d = distf(Zs[m], x0, x1, x2, xq);
                if (d <= Tstar) {
                    if (cnt < 16) myc[cnt] = (unsigned short)m;
                    ++cnt;
                }
            }
        }

        int ovf = cnt > 16 ? 1 : 0;
        ovf |= __shfl_xor(ovf, 1, 64);
        ovf |= __shfl_xor(ovf, 2, 64);

        if (!ovf) {
            // read back own 16 u16 (4 x u64), rebuild exact u64 keys
            const unsigned long long* m64 = (const unsigned long long*)myc;
            unsigned long long raw[4] = {m64[0], m64[1], m64[2], m64[3]};
            unsigned long long C[16];
            #pragma unroll
            for (int i = 0; i < 16; ++i) {
                int m = (int)((raw[i >> 2] >> ((i & 3) * 16)) & 0x3FF);
                float d = distf(Zs[m], x0, x1, x2, xq);
                unsigned long long key =
                    ((unsigned long long)__float_as_uint(d) << 32) | (unsigned)m;
                C[i] = (i < cnt) ? key : ~0ULL;
            }
            sort16(C);
            #pragma unroll
            for (int round = 1; round <= 2; round <<= 1) {
                unsigned long long o[16];
                #pragma unroll
                for (int i = 0; i < 16; ++i) o[i] = __shfl_xor(C[i], round, 64);
                #pragma unroll
                for (int i = 0; i < 16; ++i) {
                    unsigned long long b = o[15 - i];
                    C[i] = C[i] < b ? C[i] : b;
                }
                cleanup16(C);
            }
            if (sub == 0) {   // same-wave program order: all lanes' reads precede this
                #pragma unroll
                for (int i = 0; i < 16; ++i) qb[pt * QSTRIDE + i] = C[i];
            }
        } else if (sub == 0) {
            // Rare exact fallback: full serial scan with branchless insert.
            unsigned long long R[16];
            #pragma unroll
            for (int i = 0; i < 16; ++i) R[i] = ~0ULL;
            for (int m = 0; m < M_IND; ++m) {
                float d = distf(Zs[m], x0, x1, x2, xq);
                unsigned long long kk =
                    ((unsigned long long)__float_as_uint(d) << 32) | (unsigned)m;
                if (kk < R[15]) {
                    #pragma unroll
                    for (int j = 0; j < 16; ++j) {
                        unsigned long long t = R[j];
                        bool cc = kk < t;
                        R[j] = cc ? kk : t;
                        kk = cc ? t : kk;
                    }
                }
            }
            #pragma unroll
            for (int i = 0; i < 16; ++i) qb[pt * QSTRIDE + i] = R[i];
        }
    }
    __syncthreads();
    if (tid >= PTS_PER_BLK) return;

    // ---- Phase 2: local GP, one thread per point ----
    int n = blockIdx.x * PTS_PER_BLK + tid;
    int idx[KNN];
    float kv[KNN];
    float nx[KNN], ny[KNN], nz[KNN], nq[KNN];
    #pragma unroll
    for (int a = 0; a < KNN; ++a) {
        unsigned long long k = qb[tid * QSTRIDE + a];
        idx[a] = (int)(k & 0xFFFFFFFFULL);
        float d = __uint_as_float((unsigned)(k >> 32));
        kv[a] = __expf(-0.5f * d);            // lKxz entries
        float4 z = Zs[idx[a]];
        nx[a] = z.x; ny[a] = z.y; nz[a] = z.z; nq[a] = z.w;
    }

    // A = lKzz + JITTER*I (lower tri); lKzz diag carries global jitter from
    // Kzz_j = L L^T -> diag = 1 + 2*JITTER.
    float A[KNN * (KNN + 1) / 2];
    #pragma unroll
    for (int r = 0; r < KNN; ++r) {
        A[r * (r + 1) / 2 + r] = 1.0f + 2.0f * JITTER;
        #pragma unroll
        for (int c = 0; c < r; ++c) {
            float dd = nq[r] + nq[c]
                     - 2.0f * (nx[r] * nx[c] + ny[r] * ny[c] + nz[r] * nz[c]);
            dd = fmaxf(dd, 0.0f);
            A[r * (r + 1) / 2 + c] = __expf(-0.5f * dd);
        }
    }

    // In-place Cholesky; store 1/L[c][c] in the diagonal slot.
    #pragma unroll
    for (int c = 0; c < KNN; ++c) {
        float diag = A[c * (c + 1) / 2 + c];
        #pragma unroll
        for (int k = 0; k < c; ++k) {
            float l = A[c * (c + 1) / 2 + k];
            diag = fmaf(-l, l, diag);
        }
        float s = sqrtf(fmaxf(diag, 1e-12f));
        float rinv = 1.0f / s;
        A[c * (c + 1) / 2 + c] = rinv;
        #pragma unroll
        for (int r = c + 1; r < KNN; ++r) {
            float v = A[r * (r + 1) / 2 + c];
            #pragma unroll
            for (int k = 0; k < c; ++k)
                v = fmaf(-A[r * (r + 1) / 2 + k], A[c * (c + 1) / 2 + k], v);
            A[r * (r + 1) / 2 + c] = v * rinv;
        }
    }

    // Solve A w = kv (forward then backward).
    float w[KNN];
    #pragma unroll
    for (int r = 0; r < KNN; ++r) {
        float v = kv[r];
        #pragma unroll
        for (int c = 0; c < r; ++c) v = fmaf(-A[r * (r + 1) / 2 + c], w[c], v);
        w[r] = v * A[r * (r + 1) / 2 + r];
    }
    #pragma unroll
    for (int r = KNN - 1; r >= 0; --r) {
        float v = w[r];
        #pragma unroll
        for (int c = r + 1; c < KNN; ++c) v = fmaf(-A[c * (c + 1) / 2 + r], w[c], v);
        w[r] = v * A[r * (r + 1) / 2 + r];
    }

    // W lKzz W^T = w.k - JITTER*||w||^2   (A w = k, lKzz = A - JITTER*I)
    float wk = 0.f, ww = 0.f, mean = 0.f;
    #pragma unroll
    for (int a = 0; a < KNN; ++a) {
        wk = fmaf(w[a], kv[a], wk);
        ww = fmaf(w[a], w[a], ww);
        mean = fmaf(w[a], mus[idx[a]], mean);
    }

    // qs = w^T Su[idx,idx] w
    float qs = 0.f;
    if (USE_WS) {
        #pragma unroll
        for (int r = 0; r < KNN; ++r) {
            int a = idx[r];
            float wr = w[r];
            float rowacc = 0.f;
            #pragma unroll
            for (int c = 0; c < r; ++c) {
                int b = idx[c];
                int hi = a > b ? a : b;
                int lo = a > b ? b : a;
                rowacc = fmaf(w[c], P[((unsigned)hi * (hi + 1) >> 1) + lo], rowacc);
            }
            qs = fmaf(wr, fmaf(wr, P[((unsigned)a * (a + 1) >> 1) + a], 2.0f * rowacc), qs);
        }
    } else {
        // On-demand fallback: qs = sum_k (sum_a w_a * Lu[idx_a, k])^2
        int si[KNN]; float sw[KNN];
        #pragma unroll
        for (int a = 0; a < KNN; ++a) { si[a] = idx[a]; sw[a] = w[a]; }
        #pragma unroll
        for (int a = 1; a < KNN; ++a) {
            int iv = si[a]; float wv = sw[a];
            int b = a - 1;
            while (b >= 0 && si[b] > iv) { si[b + 1] = si[b]; sw[b + 1] = sw[b]; --b; }
            si[b + 1] = iv; sw[b + 1] = wv;
        }
        int s = 0;
        int kend = si[KNN - 1];
        for (int k = 0; k <= kend; ++k) {
            float v = 0.f;
            if (s < KNN && si[s] == k) {
                v = sw[s] * __expf(Lu_raw[(unsigned)k * M_IND + k]);
                ++s;
            }
            for (int a = s; a < KNN; ++a)
                v = fmaf(sw[a], Lu_raw[(unsigned)si[a] * M_IND + k], v);
            qs = fmaf(v, v, qs);
        }
    }

    float cov = 1.0f - (wk - JITTER * ww) + qs;
    float sd = sqrtf(fmaxf(cov, 0.05f));
    out[n] = mean;
    out[N_PTS + n] = sd;
}

// ---------------------------------------------------------------------------
extern "C" void kernel_launch(void* const* d_in, const int* in_sizes, int n_in,
                              void* d_out, int out_size, void* d_ws, size_t ws_size,
                              hipStream_t stream) {
    const float* X      = (const float*)d_in[0];
    const float* Z      = (const float*)d_in[1];
    const float* Lu_raw = (const float*)d_in[2];
    const float* mu     = (const float*)d_in[3];
    float* out = (float*)d_out;

    if (ws_size >= PACKED_BYTES) {
        float* P = (float*)d_ws;   // packed lower-tri Su
        su_kernel<<<SU_BLOCKS, 256, 0, stream>>>(Lu_raw, P);
        vnngp_kernel<true><<<N_PTS / PTS_PER_BLK, 512, 0, stream>>>(X, Z, mu, P, Lu_raw, out);
    } else {
        vnngp_kernel<false><<<N_PTS / PTS_PER_BLK, 512, 0, stream>>>(X, Z, mu, nullptr, Lu_raw, out);
    }
}